// Round 9
// baseline (575.625 us; speedup 1.0000x reference)
//
#include <hip/hip_runtime.h>
#include <hip/hip_bf16.h>

// Problem constants (from reference)
#define NN 50000
#define EE 800000
#define IN_F 128
#define HID 64
#define OUT_F 64
#define KK 3
#define FCW 192   // K*HID == K*OUT_F == 192

// ---------------- GEMM: C[N,192] = A[N,Kdim] @ B[Kdim,192] ----------------
__global__ __launch_bounds__(256) void gemm_tile(const float* __restrict__ A,
                                                 const float* __restrict__ B,
                                                 float* __restrict__ C,
                                                 int N, int Kdim) {
    __shared__ float sA[32 * 128];
    const int row0 = blockIdx.x * 32;
    const int tid  = threadIdx.x;
    const int lane = tid & 63;
    const int wave = tid >> 6;

    int tile_rows = N - row0;
    if (tile_rows > 32) tile_rows = 32;

    {
        const int n4 = tile_rows * Kdim / 4;
        const float4* __restrict__ src = (const float4*)(A + (long)row0 * Kdim);
        float4* dst = (float4*)sA;
        for (int i = tid; i < n4; i += 256) dst[i] = src[i];
    }
    __syncthreads();

    float acc[8][3];
#pragma unroll
    for (int r = 0; r < 8; ++r) acc[r][0] = acc[r][1] = acc[r][2] = 0.f;

    const float* __restrict__ sa = sA + wave * 8 * Kdim;
    const float* __restrict__ bp = B + lane;
#pragma unroll 2
    for (int k = 0; k < Kdim; ++k) {
        const float b0 = bp[k * FCW];
        const float b1 = bp[k * FCW + 64];
        const float b2 = bp[k * FCW + 128];
#pragma unroll
        for (int r = 0; r < 8; ++r) {
            const float av = sa[r * Kdim + k];
            acc[r][0] = fmaf(av, b0, acc[r][0]);
            acc[r][1] = fmaf(av, b1, acc[r][1]);
            acc[r][2] = fmaf(av, b2, acc[r][2]);
        }
    }

    const int rbase = row0 + wave * 8;
#pragma unroll
    for (int r = 0; r < 8; ++r) {
        const int row = rbase + r;
        if (row < N) {
            float* cp = C + (long)row * FCW + lane;
            cp[0]   = acc[r][0];
            cp[64]  = acc[r][1];
            cp[128] = acc[r][2];
        }
    }
}

// ---------------- per-edge Gaussian weights (1 thread/edge) ----------------
__global__ void edge_weights(const float2* __restrict__ pseudo,
                             const float* __restrict__ pw,   // [2,2]
                             const float* __restrict__ pb,   // [2]
                             const float* __restrict__ mu,   // [3,2]
                             const float* __restrict__ isig, // [3,2]
                             float4* __restrict__ w4, int E) {
    int e = blockIdx.x * 256 + threadIdx.x;
    if (e >= E) return;
    float2 p = pseudo[e];
    float u0 = tanhf(fmaf(p.x, pw[0], fmaf(p.y, pw[2], pb[0])));
    float u1 = tanhf(fmaf(p.x, pw[1], fmaf(p.y, pw[3], pb[1])));
    float w[KK];
#pragma unroll
    for (int k = 0; k < KK; ++k) {
        float d0 = (u0 - mu[k * 2 + 0]) * isig[k * 2 + 0];
        float d1 = (u1 - mu[k * 2 + 1]) * isig[k * 2 + 1];
        w[k] = __expf(-0.5f * (d0 * d0 + d1 * d1));
    }
    w4[e] = make_float4(w[0], w[1], w[2], 0.f);
}

// ---------------- CSR build: hist -> scan -> scatter ----------------
__global__ void zero_counts(int* __restrict__ counts, int n) {
    int i = blockIdx.x * 256 + threadIdx.x;
    if (i < n) counts[i] = 0;
}

__global__ void hist_dst(const int* __restrict__ dst, int* __restrict__ counts, int E) {
    int e = blockIdx.x * 256 + threadIdx.x;
    if (e < E) atomicAdd(&counts[dst[e]], 1);
}

// block partial sums of counts
__global__ __launch_bounds__(256) void scan_partials(const int* __restrict__ counts,
                                                     int* __restrict__ partials, int n) {
    __shared__ int s[256];
    int i = blockIdx.x * 256 + threadIdx.x;
    int v = (i < n) ? counts[i] : 0;
    s[threadIdx.x] = v;
    __syncthreads();
    for (int off = 128; off > 0; off >>= 1) {
        if (threadIdx.x < off) s[threadIdx.x] += s[threadIdx.x + off];
        __syncthreads();
    }
    if (threadIdx.x == 0) partials[blockIdx.x] = s[0];
}

// exclusive scan of partials (single thread; nblocks ~196)
__global__ void scan_top(int* __restrict__ partials, int nblocks) {
    if (threadIdx.x == 0 && blockIdx.x == 0) {
        int run = 0;
        for (int b = 0; b < nblocks; ++b) {
            int v = partials[b];
            partials[b] = run;
            run += v;
        }
    }
}

// per-block exclusive scan + partial offset -> row_ptr, cursor
__global__ __launch_bounds__(256) void scan_final(const int* __restrict__ counts,
                                                  const int* __restrict__ partials,
                                                  int* __restrict__ row_ptr,
                                                  int* __restrict__ cursor, int n) {
    __shared__ int s[256];
    int i = blockIdx.x * 256 + threadIdx.x;
    int tid = threadIdx.x;
    int v = (i < n) ? counts[i] : 0;
    s[tid] = v;
    __syncthreads();
    // Hillis-Steele inclusive scan
    for (int off = 1; off < 256; off <<= 1) {
        int t = (tid >= off) ? s[tid - off] : 0;
        __syncthreads();
        s[tid] += t;
        __syncthreads();
    }
    if (i < n) {
        int ex = s[tid] - v + partials[blockIdx.x];
        row_ptr[i] = ex;
        cursor[i]  = ex;
    }
}

__global__ void scatter_edges(const int* __restrict__ dst, int* __restrict__ cursor,
                              int* __restrict__ edge_order, int E) {
    int e = blockIdx.x * 256 + threadIdx.x;
    if (e < E) {
        int pos = atomicAdd(&cursor[dst[e]], 1);
        edge_order[pos] = e;
    }
}

// ---------------- CSR aggregation: one wave per destination node ----------------
// acc starts at bias[lane]; each output element written exactly once (no atomics).
__global__ __launch_bounds__(256) void aggregate_csr(const float* __restrict__ hp,        // [N,192]
                                                     const float4* __restrict__ w4,      // [E]
                                                     const int* __restrict__ src,
                                                     const int* __restrict__ edge_order, // [E]
                                                     const int* __restrict__ row_ptr,    // [N]
                                                     const int* __restrict__ counts,     // [N]
                                                     const float* __restrict__ bias,     // [64]
                                                     float* __restrict__ out,            // [N,64]
                                                     int N) {
    const int wave = threadIdx.x >> 6;
    const int lane = threadIdx.x & 63;
    const int node = blockIdx.x * 4 + wave;
    if (node >= N) return;

    const int begin = row_ptr[node];
    const int cnt   = counts[node];
    float acc = bias[lane];

    for (int i = 0; i < cnt; ++i) {
        const int eid = edge_order[begin + i];
        const int s   = src[eid];
        const float4 w = w4[eid];
        const float* h = hp + (long)s * FCW + lane;
        acc = fmaf(w.x, h[0], fmaf(w.y, h[64], fmaf(w.z, h[128], acc)));
    }
    out[(long)node * 64 + lane] = acc;
}

// ---------------- fallback (round-8 atomic path) ----------------
__global__ void init_bias(float* __restrict__ out,
                          const float* __restrict__ bias, int total) {
    int i = blockIdx.x * 256 + threadIdx.x;
    if (i < total) out[i] = bias[i & 63];
}

__global__ __launch_bounds__(256) void edge_aggregate2(const float* __restrict__ hp,
                                                       const float4* __restrict__ w4,
                                                       const int* __restrict__ src,
                                                       const int* __restrict__ dst,
                                                       float* __restrict__ out,
                                                       int E) {
    const int wave = threadIdx.x >> 6;
    const int lane = threadIdx.x & 63;
    const int e0 = (blockIdx.x * 4 + wave) * 2;
    const int e1 = e0 + 1;
    if (e0 >= E) return;

    const float4 wa = w4[e0];
    const int sa = src[e0];
    const int da = dst[e0];
    const float* ha = hp + (long)sa * FCW + lane;
    const float a0 = ha[0], a1 = ha[64], a2 = ha[128];

    const bool has1 = (e1 < E);
    float b0 = 0.f, b1 = 0.f, b2 = 0.f;
    float4 wb = make_float4(0.f, 0.f, 0.f, 0.f);
    int db = 0;
    if (has1) {
        wb = w4[e1];
        const int sb = src[e1];
        db = dst[e1];
        const float* hb = hp + (long)sb * FCW + lane;
        b0 = hb[0]; b1 = hb[64]; b2 = hb[128];
    }

    const float msga = fmaf(wa.x, a0, fmaf(wa.y, a1, wa.z * a2));
    atomicAdd(out + (long)da * 64 + lane, msga);
    if (has1) {
        const float msgb = fmaf(wb.x, b0, fmaf(wb.y, b1, wb.z * b2));
        atomicAdd(out + (long)db * 64 + lane, msgb);
    }
}

extern "C" void kernel_launch(void* const* d_in, const int* in_sizes, int n_in,
                              void* d_out, int out_size, void* d_ws, size_t ws_size,
                              hipStream_t stream) {
    const float*  feat   = (const float*)d_in[0];
    const float2* pseudo = (const float2*)d_in[1];
    const int*    src    = (const int*)d_in[2];
    const int*    dst    = (const int*)d_in[3];
    const float*  fc0    = (const float*)d_in[4];
    const float*  mu0    = (const float*)d_in[5];
    const float*  isig0  = (const float*)d_in[6];
    const float*  bias0  = (const float*)d_in[7];
    const float*  pw0    = (const float*)d_in[8];
    const float*  pb0    = (const float*)d_in[9];
    const float*  fc1    = (const float*)d_in[10];
    const float*  mu1    = (const float*)d_in[11];
    const float*  isig1  = (const float*)d_in[12];
    const float*  bias1  = (const float*)d_in[13];
    const float*  pw1    = (const float*)d_in[14];
    const float*  pb1    = (const float*)d_in[15];

    // workspace layout
    float* hp   = (float*)d_ws;                       // [N,192]  38.4 MB
    float* agg0 = hp + (long)NN * FCW;                // [N,64]   12.8 MB
    int* edge_order = (int*)(agg0 + (long)NN * 64);   // [E]       3.2 MB
    int* row_ptr    = edge_order + EE;                // [N]       200 KB
    int* cursor     = row_ptr + NN;                   // [N]       200 KB
    int* counts     = cursor + NN;                    // [N]       200 KB
    int* partials   = counts + NN;                    // [256]       1 KB
    const size_t need = (size_t)((char*)(partials + 256) - (char*)d_ws);

    float* out = (float*)d_out;
    // w4 scratch (no ws growth): layer-0 in d_out (dead until layer-1 writes it),
    // layer-1 in agg0 region (dead after gemm1 reads it).
    float4* w4_l0 = (float4*)d_out;
    float4* w4_l1 = (float4*)agg0;

    dim3 blk(256);
    dim3 grid_gemm((NN + 31) / 32);
    dim3 grid_ew((EE + 255) / 256);
    dim3 grid_e((EE + 255) / 256);
    const int nscan = (NN + 255) / 256;
    dim3 grid_n(nscan);
    dim3 grid_node((NN + 3) / 4);

    if (ws_size >= need) {
        // ---- CSR build (dst shared by both layers; rebuilt every call) ----
        zero_counts<<<grid_n, blk, 0, stream>>>(counts, NN);
        hist_dst<<<grid_e, blk, 0, stream>>>(dst, counts, EE);
        scan_partials<<<grid_n, blk, 0, stream>>>(counts, partials, NN);
        scan_top<<<dim3(1), dim3(64), 0, stream>>>(partials, nscan);
        scan_final<<<grid_n, blk, 0, stream>>>(counts, partials, row_ptr, cursor, NN);
        scatter_edges<<<grid_e, blk, 0, stream>>>(dst, cursor, edge_order, EE);

        // ---- layer 0 ----
        gemm_tile<<<grid_gemm, blk, 0, stream>>>(feat, fc0, hp, NN, IN_F);
        edge_weights<<<grid_ew, blk, 0, stream>>>(pseudo, pw0, pb0, mu0, isig0, w4_l0, EE);
        aggregate_csr<<<grid_node, blk, 0, stream>>>(hp, w4_l0, src, edge_order,
                                                     row_ptr, counts, bias0, agg0, NN);
        // ---- layer 1 ----
        gemm_tile<<<grid_gemm, blk, 0, stream>>>(agg0, fc1, hp, NN, HID);
        edge_weights<<<grid_ew, blk, 0, stream>>>(pseudo, pw1, pb1, mu1, isig1, w4_l1, EE);
        aggregate_csr<<<grid_node, blk, 0, stream>>>(hp, w4_l1, src, edge_order,
                                                     row_ptr, counts, bias1, out, NN);
    } else {
        // ---- fallback: round-8 atomic path ----
        dim3 grid_edges((EE + 7) / 8);
        dim3 grid_init((NN * 64 + 255) / 256);
        init_bias<<<grid_init, blk, 0, stream>>>(agg0, bias0, NN * 64);
        gemm_tile<<<grid_gemm, blk, 0, stream>>>(feat, fc0, hp, NN, IN_F);
        edge_weights<<<grid_ew, blk, 0, stream>>>(pseudo, pw0, pb0, mu0, isig0, w4_l0, EE);
        edge_aggregate2<<<grid_edges, blk, 0, stream>>>(hp, w4_l0, src, dst, agg0, EE);
        gemm_tile<<<grid_gemm, blk, 0, stream>>>(agg0, fc1, hp, NN, HID);
        edge_weights<<<grid_ew, blk, 0, stream>>>(pseudo, pw1, pb1, mu1, isig1, w4_l1, EE);
        init_bias<<<grid_init, blk, 0, stream>>>(out, bias1, NN * 64);
        edge_aggregate2<<<grid_edges, blk, 0, stream>>>(hp, w4_l1, src, dst, out, EE);
    }
}

// Round 12
// 494.840 us; speedup vs baseline: 1.1633x; 1.1633x over previous
//
#include <hip/hip_runtime.h>
#include <hip/hip_bf16.h>

// Problem constants (from reference)
#define NN 50000
#define EE 800000
#define IN_F 128
#define HID 64
#define OUT_F 64
#define KK 3
#define FCW 192   // K*HID == K*OUT_F == 192

// ---------------- GEMM: C[N,192] = A[N,Kdim] @ B[Kdim,192] ----------------
__global__ __launch_bounds__(256) void gemm_tile(const float* __restrict__ A,
                                                 const float* __restrict__ B,
                                                 float* __restrict__ C,
                                                 int N, int Kdim) {
    __shared__ float sA[32 * 128];
    const int row0 = blockIdx.x * 32;
    const int tid  = threadIdx.x;
    const int lane = tid & 63;
    const int wave = tid >> 6;

    int tile_rows = N - row0;
    if (tile_rows > 32) tile_rows = 32;

    {
        const int n4 = tile_rows * Kdim / 4;
        const float4* __restrict__ src = (const float4*)(A + (long)row0 * Kdim);
        float4* dst = (float4*)sA;
        for (int i = tid; i < n4; i += 256) dst[i] = src[i];
    }
    __syncthreads();

    float acc[8][3];
#pragma unroll
    for (int r = 0; r < 8; ++r) acc[r][0] = acc[r][1] = acc[r][2] = 0.f;

    const float* __restrict__ sa = sA + wave * 8 * Kdim;
    const float* __restrict__ bp = B + lane;
#pragma unroll 2
    for (int k = 0; k < Kdim; ++k) {
        const float b0 = bp[k * FCW];
        const float b1 = bp[k * FCW + 64];
        const float b2 = bp[k * FCW + 128];
#pragma unroll
        for (int r = 0; r < 8; ++r) {
            const float av = sa[r * Kdim + k];
            acc[r][0] = fmaf(av, b0, acc[r][0]);
            acc[r][1] = fmaf(av, b1, acc[r][1]);
            acc[r][2] = fmaf(av, b2, acc[r][2]);
        }
    }

    const int rbase = row0 + wave * 8;
#pragma unroll
    for (int r = 0; r < 8; ++r) {
        const int row = rbase + r;
        if (row < N) {
            float* cp = C + (long)row * FCW + lane;
            cp[0]   = acc[r][0];
            cp[64]  = acc[r][1];
            cp[128] = acc[r][2];
        }
    }
}

// ------- per-edge Gaussian weights, written directly to CSR position -------
__global__ void edge_weights(const float2* __restrict__ pseudo,
                             const float* __restrict__ pw,   // [2,2]
                             const float* __restrict__ pb,   // [2]
                             const float* __restrict__ mu,   // [3,2]
                             const float* __restrict__ isig, // [3,2]
                             const int* __restrict__ perm,   // [E] e -> csr pos
                             float4* __restrict__ w4p, int E) {
    int e = blockIdx.x * 256 + threadIdx.x;
    if (e >= E) return;
    float2 p = pseudo[e];
    float u0 = tanhf(fmaf(p.x, pw[0], fmaf(p.y, pw[2], pb[0])));
    float u1 = tanhf(fmaf(p.x, pw[1], fmaf(p.y, pw[3], pb[1])));
    float w[KK];
#pragma unroll
    for (int k = 0; k < KK; ++k) {
        float d0 = (u0 - mu[k * 2 + 0]) * isig[k * 2 + 0];
        float d1 = (u1 - mu[k * 2 + 1]) * isig[k * 2 + 1];
        w[k] = __expf(-0.5f * (d0 * d0 + d1 * d1));
    }
    w4p[perm[e]] = make_float4(w[0], w[1], w[2], 0.f);
}

// ---------------- CSR build: hist -> scan -> scatter ----------------
__global__ void zero_counts(int* __restrict__ counts, int n) {
    int i = blockIdx.x * 256 + threadIdx.x;
    if (i < n) counts[i] = 0;
}

__global__ void hist_dst(const int* __restrict__ dst, int* __restrict__ counts, int E) {
    int e = blockIdx.x * 256 + threadIdx.x;
    if (e < E) atomicAdd(&counts[dst[e]], 1);
}

__global__ __launch_bounds__(256) void scan_partials(const int* __restrict__ counts,
                                                     int* __restrict__ partials, int n) {
    __shared__ int s[256];
    int i = blockIdx.x * 256 + threadIdx.x;
    int v = (i < n) ? counts[i] : 0;
    s[threadIdx.x] = v;
    __syncthreads();
    for (int off = 128; off > 0; off >>= 1) {
        if (threadIdx.x < off) s[threadIdx.x] += s[threadIdx.x + off];
        __syncthreads();
    }
    if (threadIdx.x == 0) partials[blockIdx.x] = s[0];
}

__global__ void scan_top(int* __restrict__ partials, int nblocks) {
    if (threadIdx.x == 0 && blockIdx.x == 0) {
        int run = 0;
        for (int b = 0; b < nblocks; ++b) {
            int v = partials[b];
            partials[b] = run;
            run += v;
        }
    }
}

__global__ __launch_bounds__(256) void scan_final(const int* __restrict__ counts,
                                                  const int* __restrict__ partials,
                                                  int* __restrict__ row_ptr,
                                                  int* __restrict__ cursor, int n) {
    __shared__ int s[256];
    int i = blockIdx.x * 256 + threadIdx.x;
    int tid = threadIdx.x;
    int v = (i < n) ? counts[i] : 0;
    s[tid] = v;
    __syncthreads();
    for (int off = 1; off < 256; off <<= 1) {
        int t = (tid >= off) ? s[tid - off] : 0;
        __syncthreads();
        s[tid] += t;
        __syncthreads();
    }
    if (i < n) {
        int ex = s[tid] - v + partials[blockIdx.x];
        row_ptr[i] = ex;
        cursor[i]  = ex;
    }
}

// also emits perm (e -> pos) and permuted src, so aggregation streams both.
__global__ void scatter_edges(const int* __restrict__ dst, const int* __restrict__ src,
                              int* __restrict__ cursor,
                              int* __restrict__ perm, int* __restrict__ src_perm, int E) {
    int e = blockIdx.x * 256 + threadIdx.x;
    if (e < E) {
        int pos = atomicAdd(&cursor[dst[e]], 1);
        perm[e] = pos;
        src_perm[pos] = src[e];
    }
}

// -------- CSR aggregation: one wave per node, 4-edge unrolled pipeline --------
__global__ __launch_bounds__(256) void aggregate_csr(const float* __restrict__ hp,       // [N,192]
                                                     const float4* __restrict__ w4p,    // [E] csr order
                                                     const int* __restrict__ src_perm,  // [E] csr order
                                                     const int* __restrict__ row_ptr,   // [N]
                                                     const int* __restrict__ counts,    // [N]
                                                     const float* __restrict__ bias,    // [64]
                                                     float* __restrict__ out,           // [N,64]
                                                     int N) {
    const int wave = threadIdx.x >> 6;
    const int lane = threadIdx.x & 63;
    const int node = blockIdx.x * 4 + wave;
    if (node >= N) return;

    const int begin = row_ptr[node];
    const int cnt   = counts[node];
    const float4* __restrict__ wp = w4p + begin;
    const int*    __restrict__ sp = src_perm + begin;
    float acc = bias[lane];

    int i = 0;
    for (; i + 4 <= cnt; i += 4) {
        // issue all independent loads first (12 gathers + 4 w4 + 4 src in flight)
        const int s0 = sp[i], s1 = sp[i + 1], s2 = sp[i + 2], s3 = sp[i + 3];
        const float4 w0 = wp[i], w1 = wp[i + 1], w2 = wp[i + 2], w3 = wp[i + 3];
        const float* h0 = hp + (long)s0 * FCW + lane;
        const float* h1 = hp + (long)s1 * FCW + lane;
        const float* h2 = hp + (long)s2 * FCW + lane;
        const float* h3 = hp + (long)s3 * FCW + lane;
        const float a0 = h0[0], a1 = h0[64], a2 = h0[128];
        const float b0 = h1[0], b1 = h1[64], b2 = h1[128];
        const float c0 = h2[0], c1 = h2[64], c2 = h2[128];
        const float d0 = h3[0], d1 = h3[64], d2 = h3[128];
        float t0 = fmaf(w0.x, a0, fmaf(w0.y, a1, w0.z * a2));
        float t1 = fmaf(w1.x, b0, fmaf(w1.y, b1, w1.z * b2));
        float t2 = fmaf(w2.x, c0, fmaf(w2.y, c1, w2.z * c2));
        float t3 = fmaf(w3.x, d0, fmaf(w3.y, d1, w3.z * d2));
        acc += (t0 + t1) + (t2 + t3);
    }
    for (; i < cnt; ++i) {
        const int s = sp[i];
        const float4 w = wp[i];
        const float* h = hp + (long)s * FCW + lane;
        acc = fmaf(w.x, h[0], fmaf(w.y, h[64], fmaf(w.z, h[128], acc)));
    }
    out[(long)node * 64 + lane] = acc;
}

// ---------------- fallback (round-8 atomic path) ----------------
__global__ void init_bias(float* __restrict__ out,
                          const float* __restrict__ bias, int total) {
    int i = blockIdx.x * 256 + threadIdx.x;
    if (i < total) out[i] = bias[i & 63];
}

__global__ void edge_weights_lin(const float2* __restrict__ pseudo,
                                 const float* __restrict__ pw, const float* __restrict__ pb,
                                 const float* __restrict__ mu, const float* __restrict__ isig,
                                 float4* __restrict__ w4, int E) {
    int e = blockIdx.x * 256 + threadIdx.x;
    if (e >= E) return;
    float2 p = pseudo[e];
    float u0 = tanhf(fmaf(p.x, pw[0], fmaf(p.y, pw[2], pb[0])));
    float u1 = tanhf(fmaf(p.x, pw[1], fmaf(p.y, pw[3], pb[1])));
    float w[KK];
#pragma unroll
    for (int k = 0; k < KK; ++k) {
        float d0 = (u0 - mu[k * 2 + 0]) * isig[k * 2 + 0];
        float d1 = (u1 - mu[k * 2 + 1]) * isig[k * 2 + 1];
        w[k] = __expf(-0.5f * (d0 * d0 + d1 * d1));
    }
    w4[e] = make_float4(w[0], w[1], w[2], 0.f);
}

__global__ __launch_bounds__(256) void edge_aggregate2(const float* __restrict__ hp,
                                                       const float4* __restrict__ w4,
                                                       const int* __restrict__ src,
                                                       const int* __restrict__ dst,
                                                       float* __restrict__ out,
                                                       int E) {
    const int wave = threadIdx.x >> 6;
    const int lane = threadIdx.x & 63;
    const int e0 = (blockIdx.x * 4 + wave) * 2;
    const int e1 = e0 + 1;
    if (e0 >= E) return;

    const float4 wa = w4[e0];
    const int sa = src[e0];
    const int da = dst[e0];
    const float* ha = hp + (long)sa * FCW + lane;
    const float a0 = ha[0], a1 = ha[64], a2 = ha[128];

    const bool has1 = (e1 < E);
    float b0 = 0.f, b1 = 0.f, b2 = 0.f;
    float4 wb = make_float4(0.f, 0.f, 0.f, 0.f);
    int db = 0;
    if (has1) {
        wb = w4[e1];
        const int sb = src[e1];
        db = dst[e1];
        const float* hb = hp + (long)sb * FCW + lane;
        b0 = hb[0]; b1 = hb[64]; b2 = hb[128];
    }

    const float msga = fmaf(wa.x, a0, fmaf(wa.y, a1, wa.z * a2));
    atomicAdd(out + (long)da * 64 + lane, msga);
    if (has1) {
        const float msgb = fmaf(wb.x, b0, fmaf(wb.y, b1, wb.z * b2));
        atomicAdd(out + (long)db * 64 + lane, msgb);
    }
}

extern "C" void kernel_launch(void* const* d_in, const int* in_sizes, int n_in,
                              void* d_out, int out_size, void* d_ws, size_t ws_size,
                              hipStream_t stream) {
    const float*  feat   = (const float*)d_in[0];
    const float2* pseudo = (const float2*)d_in[1];
    const int*    src    = (const int*)d_in[2];
    const int*    dst    = (const int*)d_in[3];
    const float*  fc0    = (const float*)d_in[4];
    const float*  mu0    = (const float*)d_in[5];
    const float*  isig0  = (const float*)d_in[6];
    const float*  bias0  = (const float*)d_in[7];
    const float*  pw0    = (const float*)d_in[8];
    const float*  pb0    = (const float*)d_in[9];
    const float*  fc1    = (const float*)d_in[10];
    const float*  mu1    = (const float*)d_in[11];
    const float*  isig1  = (const float*)d_in[12];
    const float*  bias1  = (const float*)d_in[13];
    const float*  pw1    = (const float*)d_in[14];
    const float*  pb1    = (const float*)d_in[15];

    // workspace layout
    float* hp       = (float*)d_ws;                     // [N,192]  38.4 MB
    float* agg0     = hp + (long)NN * FCW;              // [N,64]   12.8 MB
    int*   perm     = (int*)(agg0 + (long)NN * 64);     // [E]       3.2 MB
    int*   src_perm = perm + EE;                        // [E]       3.2 MB
    int*   row_ptr  = src_perm + EE;                    // [N]       200 KB
    int*   cursor   = row_ptr + NN;                     // [N]       200 KB
    int*   counts   = cursor + NN;                      // [N]       200 KB
    int*   partials = counts + NN;                      // [256]       1 KB
    const size_t need = (size_t)((char*)(partials + 256) - (char*)d_ws);

    float* out = (float*)d_out;
    // w4 scratch (no ws growth): layer-0 in d_out (dead until final aggregate),
    // layer-1 in agg0 region (dead after gemm1 reads it). E*16B == N*64*4B exactly.
    float4* w4_l0 = (float4*)d_out;
    float4* w4_l1 = (float4*)agg0;

    dim3 blk(256);
    dim3 grid_gemm((NN + 31) / 32);
    dim3 grid_e((EE + 255) / 256);
    const int nscan = (NN + 255) / 256;
    dim3 grid_n(nscan);
    dim3 grid_node((NN + 3) / 4);

    if (ws_size >= need) {
        // ---- CSR build (dst shared by both layers) ----
        zero_counts<<<grid_n, blk, 0, stream>>>(counts, NN);
        hist_dst<<<grid_e, blk, 0, stream>>>(dst, counts, EE);
        scan_partials<<<grid_n, blk, 0, stream>>>(counts, partials, NN);
        scan_top<<<dim3(1), dim3(64), 0, stream>>>(partials, nscan);
        scan_final<<<grid_n, blk, 0, stream>>>(counts, partials, row_ptr, cursor, NN);
        scatter_edges<<<grid_e, blk, 0, stream>>>(dst, src, cursor, perm, src_perm, EE);

        // ---- layer 0 ----
        gemm_tile<<<grid_gemm, blk, 0, stream>>>(feat, fc0, hp, NN, IN_F);
        edge_weights<<<grid_e, blk, 0, stream>>>(pseudo, pw0, pb0, mu0, isig0, perm, w4_l0, EE);
        aggregate_csr<<<grid_node, blk, 0, stream>>>(hp, w4_l0, src_perm,
                                                     row_ptr, counts, bias0, agg0, NN);
        // ---- layer 1 ----
        gemm_tile<<<grid_gemm, blk, 0, stream>>>(agg0, fc1, hp, NN, HID);
        edge_weights<<<grid_e, blk, 0, stream>>>(pseudo, pw1, pb1, mu1, isig1, perm, w4_l1, EE);
        aggregate_csr<<<grid_node, blk, 0, stream>>>(hp, w4_l1, src_perm,
                                                     row_ptr, counts, bias1, out, NN);
    } else {
        // ---- fallback: round-8 atomic path ----
        dim3 grid_edges((EE + 7) / 8);
        dim3 grid_init((NN * 64 + 255) / 256);
        init_bias<<<grid_init, blk, 0, stream>>>(agg0, bias0, NN * 64);
        gemm_tile<<<grid_gemm, blk, 0, stream>>>(feat, fc0, hp, NN, IN_F);
        edge_weights_lin<<<grid_e, blk, 0, stream>>>(pseudo, pw0, pb0, mu0, isig0, w4_l0, EE);
        edge_aggregate2<<<grid_edges, blk, 0, stream>>>(hp, w4_l0, src, dst, agg0, EE);
        gemm_tile<<<grid_gemm, blk, 0, stream>>>(agg0, fc1, hp, NN, HID);
        edge_weights_lin<<<grid_e, blk, 0, stream>>>(pseudo, pw1, pb1, mu1, isig1, w4_l1, EE);
        init_bias<<<grid_init, blk, 0, stream>>>(out, bias1, NN * 64);
        edge_aggregate2<<<grid_edges, blk, 0, stream>>>(hp, w4_l1, src, dst, out, EE);
    }
}

// Round 15
// 401.542 us; speedup vs baseline: 1.4335x; 1.2323x over previous
//
#include <hip/hip_runtime.h>
#include <hip/hip_bf16.h>

// Problem constants (from reference)
#define NN 50000
#define EE 800000
#define IN_F 128
#define HID 64
#define OUT_F 64
#define KK 3
#define FCW 192   // K*HID == K*OUT_F == 192

typedef unsigned int  u32;
typedef unsigned short u16;

__device__ __forceinline__ float bf2f(u32 lo16) {            // low 16 bits = bf16
    return __uint_as_float(lo16 << 16);
}
__device__ __forceinline__ u16 f2bf(float f) {               // RNE round
    u32 u = __float_as_uint(f);
    u32 r = u + 0x7fffu + ((u >> 16) & 1u);
    return (u16)(r >> 16);
}

// ------- GEMM: C_bf16[N,192] = A_f32[N,Kdim] @ B_f32[Kdim,192] -------
__global__ __launch_bounds__(256) void gemm_tile_bf16(const float* __restrict__ A,
                                                      const float* __restrict__ B,
                                                      u16* __restrict__ C,
                                                      int N, int Kdim) {
    __shared__ float sA[32 * 128];
    const int row0 = blockIdx.x * 32;
    const int tid  = threadIdx.x;
    const int lane = tid & 63;
    const int wave = tid >> 6;

    int tile_rows = N - row0;
    if (tile_rows > 32) tile_rows = 32;

    {   // A rows are contiguous (full-K staging) -> one linear float4 copy
        const int n4 = tile_rows * Kdim / 4;
        const float4* __restrict__ src = (const float4*)(A + (long)row0 * Kdim);
        float4* dst = (float4*)sA;
        for (int i = tid; i < n4; i += 256) dst[i] = src[i];
    }
    __syncthreads();

    float acc[8][3];
#pragma unroll
    for (int r = 0; r < 8; ++r) acc[r][0] = acc[r][1] = acc[r][2] = 0.f;

    const float* __restrict__ sa = sA + wave * 8 * Kdim;
    const float* __restrict__ bp = B + lane;
#pragma unroll 2
    for (int k = 0; k < Kdim; ++k) {
        const float b0 = bp[k * FCW];
        const float b1 = bp[k * FCW + 64];
        const float b2 = bp[k * FCW + 128];
#pragma unroll
        for (int r = 0; r < 8; ++r) {
            const float av = sa[r * Kdim + k];   // wave-uniform LDS broadcast
            acc[r][0] = fmaf(av, b0, acc[r][0]);
            acc[r][1] = fmaf(av, b1, acc[r][1]);
            acc[r][2] = fmaf(av, b2, acc[r][2]);
        }
    }

    const int rbase = row0 + wave * 8;
#pragma unroll
    for (int r = 0; r < 8; ++r) {
        const int row = rbase + r;
        if (row < N) {
            u16* cp = C + (long)row * FCW + lane;
            cp[0]   = f2bf(acc[r][0]);
            cp[64]  = f2bf(acc[r][1]);
            cp[128] = f2bf(acc[r][2]);
        }
    }
}

// ---------------- CSR build: hist -> scan ----------------
__global__ void zero_counts(int* __restrict__ counts, int n) {
    int i = blockIdx.x * 256 + threadIdx.x;
    if (i < n) counts[i] = 0;
}

__global__ void hist_dst(const int* __restrict__ dst, int* __restrict__ counts, int E) {
    int e = blockIdx.x * 256 + threadIdx.x;
    if (e < E) atomicAdd(&counts[dst[e]], 1);
}

__global__ __launch_bounds__(256) void scan_partials(const int* __restrict__ counts,
                                                     int* __restrict__ partials, int n) {
    __shared__ int s[256];
    int i = blockIdx.x * 256 + threadIdx.x;
    int v = (i < n) ? counts[i] : 0;
    s[threadIdx.x] = v;
    __syncthreads();
    for (int off = 128; off > 0; off >>= 1) {
        if (threadIdx.x < off) s[threadIdx.x] += s[threadIdx.x + off];
        __syncthreads();
    }
    if (threadIdx.x == 0) partials[blockIdx.x] = s[0];
}

__global__ void scan_top(int* __restrict__ partials, int nblocks) {
    if (threadIdx.x == 0 && blockIdx.x == 0) {
        int run = 0;
        for (int b = 0; b < nblocks; ++b) {
            int v = partials[b];
            partials[b] = run;
            run += v;
        }
    }
}

__global__ __launch_bounds__(256) void scan_final(const int* __restrict__ counts,
                                                  const int* __restrict__ partials,
                                                  int* __restrict__ row_ptr,
                                                  int* __restrict__ cursor, int n) {
    __shared__ int s[256];
    int i = blockIdx.x * 256 + threadIdx.x;
    int tid = threadIdx.x;
    int v = (i < n) ? counts[i] : 0;
    s[tid] = v;
    __syncthreads();
    for (int off = 1; off < 256; off <<= 1) {
        int t = (tid >= off) ? s[tid - off] : 0;
        __syncthreads();
        s[tid] += t;
        __syncthreads();
    }
    if (i < n) {
        int ex = s[tid] - v + partials[blockIdx.x];
        row_ptr[i] = ex;
        cursor[i]  = ex;
    }
}

// ---- fused scatter + BOTH layers' Gaussian weights (bf16-packed uint4) ----
// q.x = w0_l0 | w1_l0<<16 ; q.y = w2_l0 ; q.z = w0_l1 | w1_l1<<16 ; q.w = w2_l1
__global__ void scatter_weights(const int* __restrict__ dst, const int* __restrict__ srcv,
                                const float2* __restrict__ pseudo,
                                const float* __restrict__ pw0, const float* __restrict__ pb0,
                                const float* __restrict__ mu0, const float* __restrict__ isig0,
                                const float* __restrict__ pw1, const float* __restrict__ pb1,
                                const float* __restrict__ mu1, const float* __restrict__ isig1,
                                int* __restrict__ cursor,
                                int* __restrict__ src_perm, uint4* __restrict__ wcomb, int E) {
    int e = blockIdx.x * 256 + threadIdx.x;
    if (e >= E) return;
    float2 p = pseudo[e];
    int pos = atomicAdd(&cursor[dst[e]], 1);
    src_perm[pos] = srcv[e];

    float u0 = tanhf(fmaf(p.x, pw0[0], fmaf(p.y, pw0[2], pb0[0])));
    float u1 = tanhf(fmaf(p.x, pw0[1], fmaf(p.y, pw0[3], pb0[1])));
    float v0 = tanhf(fmaf(p.x, pw1[0], fmaf(p.y, pw1[2], pb1[0])));
    float v1 = tanhf(fmaf(p.x, pw1[1], fmaf(p.y, pw1[3], pb1[1])));

    float wl0[KK], wl1[KK];
#pragma unroll
    for (int k = 0; k < KK; ++k) {
        float d0 = (u0 - mu0[k * 2 + 0]) * isig0[k * 2 + 0];
        float d1 = (u1 - mu0[k * 2 + 1]) * isig0[k * 2 + 1];
        wl0[k] = __expf(-0.5f * (d0 * d0 + d1 * d1));
        float e0 = (v0 - mu1[k * 2 + 0]) * isig1[k * 2 + 0];
        float e1 = (v1 - mu1[k * 2 + 1]) * isig1[k * 2 + 1];
        wl1[k] = __expf(-0.5f * (e0 * e0 + e1 * e1));
    }
    uint4 q;
    q.x = (u32)f2bf(wl0[0]) | ((u32)f2bf(wl0[1]) << 16);
    q.y = (u32)f2bf(wl0[2]);
    q.z = (u32)f2bf(wl1[0]) | ((u32)f2bf(wl1[1]) << 16);
    q.w = (u32)f2bf(wl1[2]);
    wcomb[pos] = q;
}

// -------- CSR aggregation (bf16 hp, packed bf16 weights), 8-edge pipeline --------
template <int LAYER>
__global__ __launch_bounds__(256) void aggregate_csr_bf16(const u16* __restrict__ hp,      // [N,192] bf16
                                                          const uint4* __restrict__ wcomb, // [E] csr order
                                                          const int* __restrict__ src_perm,// [E] csr order
                                                          const int* __restrict__ row_ptr, // [N]
                                                          const int* __restrict__ counts,  // [N]
                                                          const float* __restrict__ bias,  // [64]
                                                          float* __restrict__ out,         // [N,64]
                                                          int N) {
    const int wave = threadIdx.x >> 6;
    const int lane = threadIdx.x & 63;
    const int node = blockIdx.x * 4 + wave;
    if (node >= N) return;

    const int begin = row_ptr[node];
    const int cnt   = counts[node];
    const uint4* __restrict__ wp = wcomb + begin;
    const int*   __restrict__ sp = src_perm + begin;
    float acc = bias[lane];

    int i = 0;
    for (; i + 8 <= cnt; i += 8) {
        int s[8];
        uint4 q[8];
#pragma unroll
        for (int j = 0; j < 8; ++j) s[j] = sp[i + j];
#pragma unroll
        for (int j = 0; j < 8; ++j) q[j] = wp[i + j];
        float h0[8], h1[8], h2[8];
#pragma unroll
        for (int j = 0; j < 8; ++j) {                 // 24 independent gathers in flight
            const u16* h = hp + (long)s[j] * FCW + lane;
            h0[j] = bf2f(h[0]);
            h1[j] = bf2f(h[64]);
            h2[j] = bf2f(h[128]);
        }
        float t = 0.f;
#pragma unroll
        for (int j = 0; j < 8; ++j) {
            const u32 a = (LAYER == 0) ? q[j].x : q[j].z;
            const u32 b = (LAYER == 0) ? q[j].y : q[j].w;
            const float w0 = bf2f(a & 0xffffu);
            const float w1 = bf2f(a >> 16);
            const float w2 = bf2f(b & 0xffffu);
            t += fmaf(w0, h0[j], fmaf(w1, h1[j], w2 * h2[j]));
        }
        acc += t;
    }
    for (; i + 4 <= cnt; i += 4) {
        int s[4];
        uint4 q[4];
#pragma unroll
        for (int j = 0; j < 4; ++j) s[j] = sp[i + j];
#pragma unroll
        for (int j = 0; j < 4; ++j) q[j] = wp[i + j];
        float t = 0.f;
#pragma unroll
        for (int j = 0; j < 4; ++j) {
            const u16* h = hp + (long)s[j] * FCW + lane;
            const u32 a = (LAYER == 0) ? q[j].x : q[j].z;
            const u32 b = (LAYER == 0) ? q[j].y : q[j].w;
            t += fmaf(bf2f(a & 0xffffu), bf2f(h[0]),
                 fmaf(bf2f(a >> 16),     bf2f(h[64]),
                      bf2f(b & 0xffffu) * bf2f(h[128])));
        }
        acc += t;
    }
    for (; i < cnt; ++i) {
        const int s = sp[i];
        const uint4 q = wp[i];
        const u16* h = hp + (long)s * FCW + lane;
        const u32 a = (LAYER == 0) ? q.x : q.z;
        const u32 b = (LAYER == 0) ? q.y : q.w;
        acc = fmaf(bf2f(a & 0xffffu), bf2f(h[0]),
              fmaf(bf2f(a >> 16),     bf2f(h[64]),
              fmaf(bf2f(b & 0xffffu), bf2f(h[128]), acc)));
    }
    out[(long)node * 64 + lane] = acc;
}

extern "C" void kernel_launch(void* const* d_in, const int* in_sizes, int n_in,
                              void* d_out, int out_size, void* d_ws, size_t ws_size,
                              hipStream_t stream) {
    const float*  feat   = (const float*)d_in[0];
    const float2* pseudo = (const float2*)d_in[1];
    const int*    src    = (const int*)d_in[2];
    const int*    dst    = (const int*)d_in[3];
    const float*  fc0    = (const float*)d_in[4];
    const float*  mu0    = (const float*)d_in[5];
    const float*  isig0  = (const float*)d_in[6];
    const float*  bias0  = (const float*)d_in[7];
    const float*  pw0    = (const float*)d_in[8];
    const float*  pb0    = (const float*)d_in[9];
    const float*  fc1    = (const float*)d_in[10];
    const float*  mu1    = (const float*)d_in[11];
    const float*  isig1  = (const float*)d_in[12];
    const float*  bias1  = (const float*)d_in[13];
    const float*  pw1    = (const float*)d_in[14];
    const float*  pb1    = (const float*)d_in[15];

    // workspace layout (48.6 MB total; round-2 proved ws_size >= 51.2 MB)
    u16*   hp       = (u16*)d_ws;                       // [N,192] bf16  19.2 MB
    float* agg0     = (float*)(hp + (long)NN * FCW);    // [N,64] f32    12.8 MB (16B-aligned)
    uint4* wcomb    = (uint4*)(agg0 + (long)NN * 64);   // [E]           12.8 MB (16B-aligned)
    int*   src_perm = (int*)(wcomb + EE);               // [E]            3.2 MB
    int*   row_ptr  = src_perm + EE;                    // [N]            200 KB
    int*   cursor   = row_ptr + NN;                     // [N]            200 KB
    int*   counts   = cursor + NN;                      // [N]            200 KB
    int*   partials = counts + NN;                      // [256]            1 KB

    float* out = (float*)d_out;

    dim3 blk(256);
    dim3 grid_gemm((NN + 31) / 32);
    dim3 grid_e((EE + 255) / 256);
    const int nscan = (NN + 255) / 256;
    dim3 grid_n(nscan);
    dim3 grid_node((NN + 3) / 4);

    // ---- CSR build (dst shared by both layers) + both layers' weights ----
    zero_counts<<<grid_n, blk, 0, stream>>>(counts, NN);
    hist_dst<<<grid_e, blk, 0, stream>>>(dst, counts, EE);
    scan_partials<<<grid_n, blk, 0, stream>>>(counts, partials, NN);
    scan_top<<<dim3(1), dim3(64), 0, stream>>>(partials, nscan);
    scan_final<<<grid_n, blk, 0, stream>>>(counts, partials, row_ptr, cursor, NN);
    scatter_weights<<<grid_e, blk, 0, stream>>>(dst, src, pseudo,
                                                pw0, pb0, mu0, isig0,
                                                pw1, pb1, mu1, isig1,
                                                cursor, src_perm, wcomb, EE);

    // ---- layer 0 ----
    gemm_tile_bf16<<<grid_gemm, blk, 0, stream>>>(feat, fc0, hp, NN, IN_F);
    aggregate_csr_bf16<0><<<grid_node, blk, 0, stream>>>(hp, wcomb, src_perm,
                                                         row_ptr, counts, bias0, agg0, NN);
    // ---- layer 1 ----
    gemm_tile_bf16<<<grid_gemm, blk, 0, stream>>>(agg0, fc1, hp, NN, HID);
    aggregate_csr_bf16<1><<<grid_node, blk, 0, stream>>>(hp, wcomb, src_perm,
                                                         row_ptr, counts, bias1, out, NN);
}

// Round 16
// 373.456 us; speedup vs baseline: 1.5413x; 1.0752x over previous
//
#include <hip/hip_runtime.h>
#include <hip/hip_bf16.h>

// Problem constants (from reference)
#define NN 50000
#define EE 800000
#define IN_F 128
#define HID 64
#define KK 3
#define FCW 192   // K*HID == K*OUT_F == 192

typedef unsigned int  u32;
typedef unsigned short u16;
typedef __attribute__((ext_vector_type(8))) short bf16x8;  // 8 bf16 (4 VGPRs)
typedef __attribute__((ext_vector_type(4))) float f32x4;   // MFMA accumulator

__device__ __forceinline__ float bf2f(u32 lo16) {            // low 16 bits = bf16
    return __uint_as_float(lo16 << 16);
}
__device__ __forceinline__ u16 f2bf(float f) {               // RNE round
    u32 u = __float_as_uint(f);
    u32 r = u + 0x7fffu + ((u >> 16) & 1u);
    return (u16)(r >> 16);
}

// ---------------- f32 -> bf16 bulk convert (n4 = n/4) ----------------
__global__ void cvt_f32_bf16(const float* __restrict__ in, u16* __restrict__ out, int n4) {
    int i = blockIdx.x * 256 + threadIdx.x;
    if (i < n4) {
        float4 v = ((const float4*)in)[i];
        ushort4 o;
        o.x = f2bf(v.x); o.y = f2bf(v.y); o.z = f2bf(v.z); o.w = f2bf(v.w);
        ((ushort4*)out)[i] = o;
    }
}

// ---- pack B[Kdim,192] f32 into MFMA B-frag order, bf16 ----
// Bp[((ct*nki + ki)*64 + l)*8 + j] = bf16( B[(ki*32 + (l>>4)*8 + j)*192 + ct*16 + (l&15)] )
__global__ void pack_b(const float* __restrict__ B, u16* __restrict__ Bp, int nki) {
    int idx = blockIdx.x * 256 + threadIdx.x;
    int total = 12 * nki * 64;
    if (idx >= total) return;
    int l  = idx & 63;
    int t  = idx >> 6;
    int ki = t % nki;
    int ct = t / nki;
    int kbase = ki * 32 + (l >> 4) * 8;
    int col   = ct * 16 + (l & 15);
    u16 tmp[8];
#pragma unroll
    for (int j = 0; j < 8; ++j) tmp[j] = f2bf(B[(kbase + j) * FCW + col]);
    *(uint4*)(Bp + (long)idx * 8) = *(uint4*)tmp;
}

// ---------------- MFMA GEMM: C_bf16[N,192] = A_bf16[N,Kdim] @ Bpack ----------------
// block 256 = 4 waves; wave handles 16 rows x 192 cols = 12 16x16 tiles.
// A-frag: lane l -> A[row0 + (l&15)][ki*32 + (l>>4)*8 + j]  (16B contiguous load)
// B-frag: lane l -> B[ki*32 + (l>>4)*8 + j][ct*16 + (l&15)] (prepacked 16B load)
// C-frag: lane l, reg r -> C[row0 + (l>>4)*4 + r][ct*16 + (l&15)]   [guide §3, m89]
__global__ __launch_bounds__(256) void gemm_mfma(const u16* __restrict__ A,
                                                 const u16* __restrict__ Bp,
                                                 u16* __restrict__ C,
                                                 int N, int nki) {
    const int wave = threadIdx.x >> 6;
    const int lane = threadIdx.x & 63;
    const int row0 = blockIdx.x * 64 + wave * 16;
    const int Kdim = nki * 32;

    int arow = row0 + (lane & 15);
    if (arow >= N) arow = N - 1;                 // clamp; stores masked below
    const u16* __restrict__ ap = A + (long)arow * Kdim + (lane >> 4) * 8;

    f32x4 acc[12];
#pragma unroll
    for (int t = 0; t < 12; ++t) acc[t] = (f32x4){0.f, 0.f, 0.f, 0.f};

    for (int ki = 0; ki < nki; ++ki) {
        const bf16x8 afrag = *(const bf16x8*)(ap + ki * 32);
        const u16* __restrict__ bbase = Bp + ((long)ki * 64 + lane) * 8;
#pragma unroll
        for (int ct = 0; ct < 12; ++ct) {
            const bf16x8 bfrag = *(const bf16x8*)(bbase + (long)ct * nki * 64 * 8);
            acc[ct] = __builtin_amdgcn_mfma_f32_16x16x32_bf16(afrag, bfrag, acc[ct], 0, 0, 0);
        }
    }

    const int crow0 = row0 + (lane >> 4) * 4;
    const int ccol  = lane & 15;
#pragma unroll
    for (int ct = 0; ct < 12; ++ct) {
#pragma unroll
        for (int r = 0; r < 4; ++r) {
            const int row = crow0 + r;
            if (row < N) C[(long)row * FCW + ct * 16 + ccol] = f2bf(acc[ct][r]);
        }
    }
}

// ---------------- CSR build: hist -> scan ----------------
__global__ void zero_counts(int* __restrict__ counts, int n) {
    int i = blockIdx.x * 256 + threadIdx.x;
    if (i < n) counts[i] = 0;
}

__global__ void hist_dst(const int* __restrict__ dst, int* __restrict__ counts, int E) {
    int e = blockIdx.x * 256 + threadIdx.x;
    if (e < E) atomicAdd(&counts[dst[e]], 1);
}

__global__ __launch_bounds__(256) void scan_partials(const int* __restrict__ counts,
                                                     int* __restrict__ partials, int n) {
    __shared__ int s[256];
    int i = blockIdx.x * 256 + threadIdx.x;
    int v = (i < n) ? counts[i] : 0;
    s[threadIdx.x] = v;
    __syncthreads();
    for (int off = 128; off > 0; off >>= 1) {
        if (threadIdx.x < off) s[threadIdx.x] += s[threadIdx.x + off];
        __syncthreads();
    }
    if (threadIdx.x == 0) partials[blockIdx.x] = s[0];
}

__global__ void scan_top(int* __restrict__ partials, int nblocks) {
    if (threadIdx.x == 0 && blockIdx.x == 0) {
        int run = 0;
        for (int b = 0; b < nblocks; ++b) {
            int v = partials[b];
            partials[b] = run;
            run += v;
        }
    }
}

__global__ __launch_bounds__(256) void scan_final(const int* __restrict__ counts,
                                                  const int* __restrict__ partials,
                                                  int* __restrict__ row_ptr,
                                                  int* __restrict__ cursor, int n) {
    __shared__ int s[256];
    int i = blockIdx.x * 256 + threadIdx.x;
    int tid = threadIdx.x;
    int v = (i < n) ? counts[i] : 0;
    s[tid] = v;
    __syncthreads();
    for (int off = 1; off < 256; off <<= 1) {
        int t = (tid >= off) ? s[tid - off] : 0;
        __syncthreads();
        s[tid] += t;
        __syncthreads();
    }
    if (i < n) {
        int ex = s[tid] - v + partials[blockIdx.x];
        row_ptr[i] = ex;
        cursor[i]  = ex;
    }
}

// ---- fused scatter + BOTH layers' Gaussian weights (bf16-packed uint4) ----
__global__ void scatter_weights(const int* __restrict__ dst, const int* __restrict__ srcv,
                                const float2* __restrict__ pseudo,
                                const float* __restrict__ pw0, const float* __restrict__ pb0,
                                const float* __restrict__ mu0, const float* __restrict__ isig0,
                                const float* __restrict__ pw1, const float* __restrict__ pb1,
                                const float* __restrict__ mu1, const float* __restrict__ isig1,
                                int* __restrict__ cursor,
                                int* __restrict__ src_perm, uint4* __restrict__ wcomb, int E) {
    int e = blockIdx.x * 256 + threadIdx.x;
    if (e >= E) return;
    float2 p = pseudo[e];
    int pos = atomicAdd(&cursor[dst[e]], 1);
    src_perm[pos] = srcv[e];

    float u0 = tanhf(fmaf(p.x, pw0[0], fmaf(p.y, pw0[2], pb0[0])));
    float u1 = tanhf(fmaf(p.x, pw0[1], fmaf(p.y, pw0[3], pb0[1])));
    float v0 = tanhf(fmaf(p.x, pw1[0], fmaf(p.y, pw1[2], pb1[0])));
    float v1 = tanhf(fmaf(p.x, pw1[1], fmaf(p.y, pw1[3], pb1[1])));

    float wl0[KK], wl1[KK];
#pragma unroll
    for (int k = 0; k < KK; ++k) {
        float d0 = (u0 - mu0[k * 2 + 0]) * isig0[k * 2 + 0];
        float d1 = (u1 - mu0[k * 2 + 1]) * isig0[k * 2 + 1];
        wl0[k] = __expf(-0.5f * (d0 * d0 + d1 * d1));
        float e0 = (v0 - mu1[k * 2 + 0]) * isig1[k * 2 + 0];
        float e1 = (v1 - mu1[k * 2 + 1]) * isig1[k * 2 + 1];
        wl1[k] = __expf(-0.5f * (e0 * e0 + e1 * e1));
    }
    uint4 q;
    q.x = (u32)f2bf(wl0[0]) | ((u32)f2bf(wl0[1]) << 16);
    q.y = (u32)f2bf(wl0[2]);
    q.z = (u32)f2bf(wl1[0]) | ((u32)f2bf(wl1[1]) << 16);
    q.w = (u32)f2bf(wl1[2]);
    wcomb[pos] = q;
}

// -------- CSR aggregation (bf16 hp, packed bf16 weights), 8-edge pipeline --------
// BFOUT: write bf16 (layer 0, feeds MFMA gemm) or f32 (final output).
template <int LAYER, int BFOUT>
__global__ __launch_bounds__(256) void aggregate_csr_bf16(const u16* __restrict__ hp,
                                                          const uint4* __restrict__ wcomb,
                                                          const int* __restrict__ src_perm,
                                                          const int* __restrict__ row_ptr,
                                                          const int* __restrict__ counts,
                                                          const float* __restrict__ bias,
                                                          void* __restrict__ outv,
                                                          int N) {
    const int wave = threadIdx.x >> 6;
    const int lane = threadIdx.x & 63;
    const int node = blockIdx.x * 4 + wave;
    if (node >= N) return;

    const int begin = row_ptr[node];
    const int cnt   = counts[node];
    const uint4* __restrict__ wp = wcomb + begin;
    const int*   __restrict__ sp = src_perm + begin;
    float acc = bias[lane];

    int i = 0;
    for (; i + 8 <= cnt; i += 8) {
        int s[8];
        uint4 q[8];
#pragma unroll
        for (int j = 0; j < 8; ++j) s[j] = sp[i + j];
#pragma unroll
        for (int j = 0; j < 8; ++j) q[j] = wp[i + j];
        float h0[8], h1[8], h2[8];
#pragma unroll
        for (int j = 0; j < 8; ++j) {                 // 24 independent gathers in flight
            const u16* h = hp + (long)s[j] * FCW + lane;
            h0[j] = bf2f(h[0]);
            h1[j] = bf2f(h[64]);
            h2[j] = bf2f(h[128]);
        }
        float t = 0.f;
#pragma unroll
        for (int j = 0; j < 8; ++j) {
            const u32 a = (LAYER == 0) ? q[j].x : q[j].z;
            const u32 b = (LAYER == 0) ? q[j].y : q[j].w;
            t += fmaf(bf2f(a & 0xffffu), h0[j],
                 fmaf(bf2f(a >> 16),     h1[j],
                      bf2f(b & 0xffffu) * h2[j]));
        }
        acc += t;
    }
    for (; i < cnt; ++i) {
        const int s = sp[i];
        const uint4 q = wp[i];
        const u16* h = hp + (long)s * FCW + lane;
        const u32 a = (LAYER == 0) ? q.x : q.z;
        const u32 b = (LAYER == 0) ? q.y : q.w;
        acc = fmaf(bf2f(a & 0xffffu), bf2f(h[0]),
              fmaf(bf2f(a >> 16),     bf2f(h[64]),
              fmaf(bf2f(b & 0xffffu), bf2f(h[128]), acc)));
    }
    if (BFOUT) ((u16*)outv)[(long)node * 64 + lane] = f2bf(acc);
    else       ((float*)outv)[(long)node * 64 + lane] = acc;
}

extern "C" void kernel_launch(void* const* d_in, const int* in_sizes, int n_in,
                              void* d_out, int out_size, void* d_ws, size_t ws_size,
                              hipStream_t stream) {
    const float*  feat   = (const float*)d_in[0];
    const float2* pseudo = (const float2*)d_in[1];
    const int*    src    = (const int*)d_in[2];
    const int*    dst    = (const int*)d_in[3];
    const float*  fc0    = (const float*)d_in[4];
    const float*  mu0    = (const float*)d_in[5];
    const float*  isig0  = (const float*)d_in[6];
    const float*  bias0  = (const float*)d_in[7];
    const float*  pw0    = (const float*)d_in[8];
    const float*  pb0    = (const float*)d_in[9];
    const float*  fc1    = (const float*)d_in[10];
    const float*  mu1    = (const float*)d_in[11];
    const float*  isig1  = (const float*)d_in[12];
    const float*  bias1  = (const float*)d_in[13];
    const float*  pw1    = (const float*)d_in[14];
    const float*  pb1    = (const float*)d_in[15];

    // workspace layout (~42.3 MB; round-2 proved ws_size >= 51.2 MB)
    u16*   hp       = (u16*)d_ws;                       // [N,192] bf16  19.2 MB
    u16*   agg0bf   = hp + (long)NN * FCW;              // [N,64]  bf16   6.4 MB
    uint4* wcomb    = (uint4*)(agg0bf + (long)NN * 64); // [E]           12.8 MB
    int*   src_perm = (int*)(wcomb + EE);               // [E]            3.2 MB
    int*   row_ptr  = src_perm + EE;                    // [N]            200 KB
    int*   cursor   = row_ptr + NN;                     // [N]            200 KB
    int*   counts   = cursor + NN;                      // [N]            200 KB
    int*   partials = counts + NN;                      // [256]            1 KB
    u16*   Bp0      = (u16*)(partials + 256);           // 12*4*64*8 bf16  48 KB
    u16*   Bp1      = Bp0 + 12 * 4 * 64 * 8;            // 12*2*64*8 bf16  24 KB

    float* out = (float*)d_out;
    // feat-bf16 scratch lives in d_out ([N,128] bf16 == [N,64] f32 bytes);
    // dead after gemm0, final aggregate fully rewrites d_out.
    u16* featbf = (u16*)d_out;

    dim3 blk(256);
    dim3 grid_gemm((NN + 63) / 64);
    dim3 grid_e((EE + 255) / 256);
    const int nscan = (NN + 255) / 256;
    dim3 grid_n(nscan);
    dim3 grid_node((NN + 3) / 4);
    dim3 grid_cvt((NN * IN_F / 4 + 255) / 256);

    // ---- prep: convert feat, pack fc0/fc1 into MFMA B-frag order ----
    cvt_f32_bf16<<<grid_cvt, blk, 0, stream>>>(feat, featbf, NN * IN_F / 4);
    pack_b<<<dim3(12), blk, 0, stream>>>(fc0, Bp0, 4);
    pack_b<<<dim3(6),  blk, 0, stream>>>(fc1, Bp1, 2);

    // ---- CSR build (dst shared by both layers) + both layers' weights ----
    zero_counts<<<grid_n, blk, 0, stream>>>(counts, NN);
    hist_dst<<<grid_e, blk, 0, stream>>>(dst, counts, EE);
    scan_partials<<<grid_n, blk, 0, stream>>>(counts, partials, NN);
    scan_top<<<dim3(1), dim3(64), 0, stream>>>(partials, nscan);
    scan_final<<<grid_n, blk, 0, stream>>>(counts, partials, row_ptr, cursor, NN);
    scatter_weights<<<grid_e, blk, 0, stream>>>(dst, src, pseudo,
                                                pw0, pb0, mu0, isig0,
                                                pw1, pb1, mu1, isig1,
                                                cursor, src_perm, wcomb, EE);

    // ---- layer 0 ----
    gemm_mfma<<<grid_gemm, blk, 0, stream>>>(featbf, Bp0, hp, NN, 4);
    aggregate_csr_bf16<0, 1><<<grid_node, blk, 0, stream>>>(hp, wcomb, src_perm,
                                                            row_ptr, counts, bias0,
                                                            (void*)agg0bf, NN);
    // ---- layer 1 ----
    gemm_mfma<<<grid_gemm, blk, 0, stream>>>(agg0bf, Bp1, hp, NN, 2);
    aggregate_csr_bf16<1, 0><<<grid_node, blk, 0, stream>>>(hp, wcomb, src_perm,
                                                            row_ptr, counts, bias1,
                                                            (void*)out, NN);
}

// Round 18
// 337.895 us; speedup vs baseline: 1.7036x; 1.1052x over previous
//
#include <hip/hip_runtime.h>
#include <hip/hip_bf16.h>

// Problem constants (from reference)
#define NN 50000
#define EE 800000
#define IN_F 128
#define HID 64
#define KK 3
#define FCW 192   // K*HID == K*OUT_F == 192

typedef unsigned int  u32;
typedef unsigned short u16;
typedef __attribute__((ext_vector_type(8))) short bf16x8;  // 8 bf16 (4 VGPRs)
typedef __attribute__((ext_vector_type(4))) float f32x4;   // MFMA accumulator

__device__ __forceinline__ float bf2f(u32 lo16) {            // low 16 bits = bf16
    return __uint_as_float(lo16 << 16);
}
__device__ __forceinline__ u16 f2bf(float f) {               // RNE round
    u32 u = __float_as_uint(f);
    u32 r = u + 0x7fffu + ((u >> 16) & 1u);
    return (u16)(r >> 16);
}

// ---- pack B[Kdim,192] f32 into MFMA B-frag order, bf16 ----
// Bp[((ct*nki + ki)*64 + l)*8 + j] = bf16( B[(ki*32 + (l>>4)*8 + j)*192 + ct*16 + (l&15)] )
__global__ void pack_b(const float* __restrict__ B, u16* __restrict__ Bp, int nki) {
    int idx = blockIdx.x * 256 + threadIdx.x;
    int total = 12 * nki * 64;
    if (idx >= total) return;
    int l  = idx & 63;
    int t  = idx >> 6;
    int ki = t % nki;
    int ct = t / nki;
    int kbase = ki * 32 + (l >> 4) * 8;
    int col   = ct * 16 + (l & 15);
    u16 tmp[8];
#pragma unroll
    for (int j = 0; j < 8; ++j) tmp[j] = f2bf(B[(kbase + j) * FCW + col]);
    *(uint4*)(Bp + (long)idx * 8) = *(uint4*)tmp;
}

// ---------------- MFMA GEMM: C_bf16[N,192] = A[N,Kdim] @ Bpack ----------------
// AF32: A is f32 (converted to bf16 in-register) or bf16.
// block 256 = 4 waves; wave handles 16 rows x 192 cols = 12 16x16 tiles.
// A-frag: lane l -> A[row0 + (l&15)][ki*32 + (l>>4)*8 + j]
// B-frag: lane l -> B[ki*32 + (l>>4)*8 + j][ct*16 + (l&15)] (prepacked 16B load)
// C-frag: lane l, reg r -> C[row0 + (l>>4)*4 + r][ct*16 + (l&15)]   [guide §3, m89]
template <int AF32>
__global__ __launch_bounds__(256) void gemm_mfma(const void* __restrict__ Av,
                                                 const u16* __restrict__ Bp,
                                                 u16* __restrict__ C,
                                                 int N, int nki) {
    const int wave = threadIdx.x >> 6;
    const int lane = threadIdx.x & 63;
    const int row0 = blockIdx.x * 64 + wave * 16;
    const int Kdim = nki * 32;

    int arow = row0 + (lane & 15);
    if (arow >= N) arow = N - 1;                 // clamp; stores masked below

    f32x4 acc[12];
#pragma unroll
    for (int t = 0; t < 12; ++t) acc[t] = (f32x4){0.f, 0.f, 0.f, 0.f};

    for (int ki = 0; ki < nki; ++ki) {
        bf16x8 afrag;
        if (AF32) {
            const float* ap = (const float*)Av + (long)arow * Kdim + (lane >> 4) * 8 + ki * 32;
            float4 v0 = *(const float4*)ap;
            float4 v1 = *(const float4*)(ap + 4);
            u16 tmp[8];
            tmp[0] = f2bf(v0.x); tmp[1] = f2bf(v0.y); tmp[2] = f2bf(v0.z); tmp[3] = f2bf(v0.w);
            tmp[4] = f2bf(v1.x); tmp[5] = f2bf(v1.y); tmp[6] = f2bf(v1.z); tmp[7] = f2bf(v1.w);
            afrag = *(const bf16x8*)tmp;
        } else {
            const u16* ap = (const u16*)Av + (long)arow * Kdim + (lane >> 4) * 8 + ki * 32;
            afrag = *(const bf16x8*)ap;
        }
        const u16* __restrict__ bbase = Bp + ((long)ki * 64 + lane) * 8;
#pragma unroll
        for (int ct = 0; ct < 12; ++ct) {
            const bf16x8 bfrag = *(const bf16x8*)(bbase + (long)ct * nki * 64 * 8);
            acc[ct] = __builtin_amdgcn_mfma_f32_16x16x32_bf16(afrag, bfrag, acc[ct], 0, 0, 0);
        }
    }

    const int crow0 = row0 + (lane >> 4) * 4;
    const int ccol  = lane & 15;
#pragma unroll
    for (int ct = 0; ct < 12; ++ct) {
#pragma unroll
        for (int r = 0; r < 4; ++r) {
            const int row = crow0 + r;
            if (row < N) C[(long)row * FCW + ct * 16 + ccol] = f2bf(acc[ct][r]);
        }
    }
}

// ---------------- CSR build: hist -> scan ----------------
__global__ void zero_counts(int* __restrict__ counts, int n) {
    int i = blockIdx.x * 256 + threadIdx.x;
    if (i < n) counts[i] = 0;
}

__global__ void hist_dst(const int* __restrict__ dst, int* __restrict__ counts, int E) {
    int e = blockIdx.x * 256 + threadIdx.x;
    if (e < E) atomicAdd(&counts[dst[e]], 1);
}

__global__ __launch_bounds__(256) void scan_partials(const int* __restrict__ counts,
                                                     int* __restrict__ partials, int n) {
    __shared__ int s[256];
    int i = blockIdx.x * 256 + threadIdx.x;
    int v = (i < n) ? counts[i] : 0;
    s[threadIdx.x] = v;
    __syncthreads();
    for (int off = 128; off > 0; off >>= 1) {
        if (threadIdx.x < off) s[threadIdx.x] += s[threadIdx.x + off];
        __syncthreads();
    }
    if (threadIdx.x == 0) partials[blockIdx.x] = s[0];
}

// parallel exclusive scan of partials (single 256-thread block; nblocks <= 256)
__global__ __launch_bounds__(256) void scan_top(int* __restrict__ partials, int nblocks) {
    __shared__ int s[256];
    int tid = threadIdx.x;
    int v = (tid < nblocks) ? partials[tid] : 0;
    s[tid] = v;
    __syncthreads();
    for (int off = 1; off < 256; off <<= 1) {
        int t = (tid >= off) ? s[tid - off] : 0;
        __syncthreads();
        s[tid] += t;
        __syncthreads();
    }
    if (tid < nblocks) partials[tid] = s[tid] - v;   // exclusive
}

__global__ __launch_bounds__(256) void scan_final(const int* __restrict__ counts,
                                                  const int* __restrict__ partials,
                                                  int* __restrict__ row_ptr,
                                                  int* __restrict__ cursor, int n) {
    __shared__ int s[256];
    int i = blockIdx.x * 256 + threadIdx.x;
    int tid = threadIdx.x;
    int v = (i < n) ? counts[i] : 0;
    s[tid] = v;
    __syncthreads();
    for (int off = 1; off < 256; off <<= 1) {
        int t = (tid >= off) ? s[tid - off] : 0;
        __syncthreads();
        s[tid] += t;
        __syncthreads();
    }
    if (i < n) {
        int ex = s[tid] - v + partials[blockIdx.x];
        row_ptr[i] = ex;
        cursor[i]  = ex;
    }
}

// ---- fused scatter: ONE uint4 record per edge = (src, 6 bf16 weights) ----
// q.x = src ; q.y = w0_l0 | w1_l0<<16 ; q.z = w2_l0 | w0_l1<<16 ; q.w = w1_l1 | w2_l1<<16
__global__ void scatter_weights(const int* __restrict__ dst, const int* __restrict__ srcv,
                                const float2* __restrict__ pseudo,
                                const float* __restrict__ pw0, const float* __restrict__ pb0,
                                const float* __restrict__ mu0, const float* __restrict__ isig0,
                                const float* __restrict__ pw1, const float* __restrict__ pb1,
                                const float* __restrict__ mu1, const float* __restrict__ isig1,
                                int* __restrict__ cursor,
                                uint4* __restrict__ rec, int E) {
    int e = blockIdx.x * 256 + threadIdx.x;
    if (e >= E) return;
    float2 p = pseudo[e];
    int pos = atomicAdd(&cursor[dst[e]], 1);

    float u0 = tanhf(fmaf(p.x, pw0[0], fmaf(p.y, pw0[2], pb0[0])));
    float u1 = tanhf(fmaf(p.x, pw0[1], fmaf(p.y, pw0[3], pb0[1])));
    float v0 = tanhf(fmaf(p.x, pw1[0], fmaf(p.y, pw1[2], pb1[0])));
    float v1 = tanhf(fmaf(p.x, pw1[1], fmaf(p.y, pw1[3], pb1[1])));

    float wl0[KK], wl1[KK];
#pragma unroll
    for (int k = 0; k < KK; ++k) {
        float d0 = (u0 - mu0[k * 2 + 0]) * isig0[k * 2 + 0];
        float d1 = (u1 - mu0[k * 2 + 1]) * isig0[k * 2 + 1];
        wl0[k] = __expf(-0.5f * (d0 * d0 + d1 * d1));
        float e0 = (v0 - mu1[k * 2 + 0]) * isig1[k * 2 + 0];
        float e1 = (v1 - mu1[k * 2 + 1]) * isig1[k * 2 + 1];
        wl1[k] = __expf(-0.5f * (e0 * e0 + e1 * e1));
    }
    uint4 q;
    q.x = (u32)srcv[e];
    q.y = (u32)f2bf(wl0[0]) | ((u32)f2bf(wl0[1]) << 16);
    q.z = (u32)f2bf(wl0[2]) | ((u32)f2bf(wl1[0]) << 16);
    q.w = (u32)f2bf(wl1[1]) | ((u32)f2bf(wl1[2]) << 16);
    rec[pos] = q;
}

// -------- CSR aggregation: stream one 16B record/edge, 8-edge gather pipeline --------
// BFOUT: write bf16 (layer 0, feeds MFMA gemm) or f32 (final output).
template <int LAYER, int BFOUT>
__global__ __launch_bounds__(256) void aggregate_csr_bf16(const u16* __restrict__ hp,
                                                          const uint4* __restrict__ rec,
                                                          const int* __restrict__ row_ptr,
                                                          const int* __restrict__ counts,
                                                          const float* __restrict__ bias,
                                                          void* __restrict__ outv,
                                                          int N) {
    const int wave = threadIdx.x >> 6;
    const int lane = threadIdx.x & 63;
    const int node = blockIdx.x * 4 + wave;
    if (node >= N) return;

    const int begin = row_ptr[node];
    const int cnt   = counts[node];
    const uint4* __restrict__ rp = rec + begin;
    float acc = bias[lane];

    int i = 0;
    for (; i + 8 <= cnt; i += 8) {
        uint4 q[8];
#pragma unroll
        for (int j = 0; j < 8; ++j) q[j] = rp[i + j];
        float h0[8], h1[8], h2[8];
#pragma unroll
        for (int j = 0; j < 8; ++j) {                 // 24 independent gathers in flight
            const u16* h = hp + (long)(int)q[j].x * FCW + lane;
            h0[j] = bf2f(h[0]);
            h1[j] = bf2f(h[64]);
            h2[j] = bf2f(h[128]);
        }
        float t = 0.f;
#pragma unroll
        for (int j = 0; j < 8; ++j) {
            float w0, w1, w2;
            if (LAYER == 0) {
                w0 = bf2f(q[j].y & 0xffffu); w1 = bf2f(q[j].y >> 16); w2 = bf2f(q[j].z & 0xffffu);
            } else {
                w0 = bf2f(q[j].z >> 16); w1 = bf2f(q[j].w & 0xffffu); w2 = bf2f(q[j].w >> 16);
            }
            t += fmaf(w0, h0[j], fmaf(w1, h1[j], w2 * h2[j]));
        }
        acc += t;
    }
    for (; i < cnt; ++i) {
        const uint4 q = rp[i];
        const u16* h = hp + (long)(int)q.x * FCW + lane;
        float w0, w1, w2;
        if (LAYER == 0) {
            w0 = bf2f(q.y & 0xffffu); w1 = bf2f(q.y >> 16); w2 = bf2f(q.z & 0xffffu);
        } else {
            w0 = bf2f(q.z >> 16); w1 = bf2f(q.w & 0xffffu); w2 = bf2f(q.w >> 16);
        }
        acc = fmaf(w0, bf2f(h[0]), fmaf(w1, bf2f(h[64]), fmaf(w2, bf2f(h[128]), acc)));
    }
    if (BFOUT) ((u16*)outv)[(long)node * 64 + lane] = f2bf(acc);
    else       ((float*)outv)[(long)node * 64 + lane] = acc;
}

extern "C" void kernel_launch(void* const* d_in, const int* in_sizes, int n_in,
                              void* d_out, int out_size, void* d_ws, size_t ws_size,
                              hipStream_t stream) {
    const float*  feat   = (const float*)d_in[0];
    const float2* pseudo = (const float2*)d_in[1];
    const int*    src    = (const int*)d_in[2];
    const int*    dst    = (const int*)d_in[3];
    const float*  fc0    = (const float*)d_in[4];
    const float*  mu0    = (const float*)d_in[5];
    const float*  isig0  = (const float*)d_in[6];
    const float*  bias0  = (const float*)d_in[7];
    const float*  pw0    = (const float*)d_in[8];
    const float*  pb0    = (const float*)d_in[9];
    const float*  fc1    = (const float*)d_in[10];
    const float*  mu1    = (const float*)d_in[11];
    const float*  isig1  = (const float*)d_in[12];
    const float*  bias1  = (const float*)d_in[13];
    const float*  pw1    = (const float*)d_in[14];
    const float*  pb1    = (const float*)d_in[15];

    // workspace layout (~39 MB; round-2 proved ws_size >= 51.2 MB)
    u16*   hp       = (u16*)d_ws;                       // [N,192] bf16  19.2 MB
    u16*   agg0bf   = hp + (long)NN * FCW;              // [N,64]  bf16   6.4 MB
    uint4* rec      = (uint4*)(agg0bf + (long)NN * 64); // [E]           12.8 MB
    int*   row_ptr  = (int*)(rec + EE);                 // [N]            200 KB
    int*   cursor   = row_ptr + NN;                     // [N]            200 KB
    int*   counts   = cursor + NN;                      // [N]            200 KB
    int*   partials = counts + NN;                      // [256]            1 KB
    u16*   Bp0      = (u16*)(partials + 256);           // 12*4*64*8 bf16  48 KB
    u16*   Bp1      = Bp0 + 12 * 4 * 64 * 8;            // 12*2*64*8 bf16  24 KB

    float* out = (float*)d_out;

    dim3 blk(256);
    dim3 grid_gemm((NN + 63) / 64);
    dim3 grid_e((EE + 255) / 256);
    const int nscan = (NN + 255) / 256;
    dim3 grid_n(nscan);
    dim3 grid_node((NN + 3) / 4);

    // ---- prep: pack fc0/fc1 into MFMA B-frag order ----
    pack_b<<<dim3(12), blk, 0, stream>>>(fc0, Bp0, 4);
    pack_b<<<dim3(6),  blk, 0, stream>>>(fc1, Bp1, 2);

    // ---- CSR build (dst shared by both layers) + both layers' weights ----
    zero_counts<<<grid_n, blk, 0, stream>>>(counts, NN);
    hist_dst<<<grid_e, blk, 0, stream>>>(dst, counts, EE);
    scan_partials<<<grid_n, blk, 0, stream>>>(counts, partials, NN);
    scan_top<<<dim3(1), blk, 0, stream>>>(partials, nscan);
    scan_final<<<grid_n, blk, 0, stream>>>(counts, partials, row_ptr, cursor, NN);
    scatter_weights<<<grid_e, blk, 0, stream>>>(dst, src, pseudo,
                                                pw0, pb0, mu0, isig0,
                                                pw1, pb1, mu1, isig1,
                                                cursor, rec, EE);

    // ---- layer 0 ----  (A = feat f32, converted in-register)
    gemm_mfma<1><<<grid_gemm, blk, 0, stream>>>((const void*)feat, Bp0, hp, NN, 4);
    aggregate_csr_bf16<0, 1><<<grid_node, blk, 0, stream>>>(hp, rec, row_ptr, counts,
                                                            bias0, (void*)agg0bf, NN);
    // ---- layer 1 ----  (A = agg0bf bf16)
    gemm_mfma<0><<<grid_gemm, blk, 0, stream>>>((const void*)agg0bf, Bp1, hp, NN, 2);
    aggregate_csr_bf16<1, 0><<<grid_node, blk, 0, stream>>>(hp, rec, row_ptr, counts,
                                                            bias1, (void*)out, NN);
}